// Round 2
// baseline (15200.385 us; speedup 1.0000x reference)
//
#include <hip/hip_runtime.h>
#include <cmath>

#define DT_     0.054f
#define GAMMA_  4.9f
#define EPS_    4.8f
#define B_      64
#define T_      1024
#define I_      256
#define H_      512
#define WS_     1280   // W row stride = I + 2H = 256 + 1024  (NOT 1536!)

// ---------------------------------------------------------------------------
// Kernel A: transpose W[:, 256:1280] (512 h x 1024 k, row-major within W) into
// WcT[k][h] (1024 x 512) so the scan's weight reads are coalesced along h.
// k in [0,512) -> Wz^T, k in [512,1024) -> Wy^T (contiguous in W).
// ---------------------------------------------------------------------------
__global__ __launch_bounds__(256) void wtrans_kernel(const float* __restrict__ W,
                                                     float* __restrict__ Wc) {
    __shared__ float tile[32][33];
    const int k0 = blockIdx.x * 32;
    const int h0 = blockIdx.y * 32;
    const int tx = threadIdx.x;   // 0..31
    const int ty = threadIdx.y;   // 0..7
#pragma unroll
    for (int j = 0; j < 4; ++j) {
        const int hh = ty + j * 8;
        tile[hh][tx] = W[(h0 + hh) * WS_ + 256 + k0 + tx];   // coalesced along k
    }
    __syncthreads();
#pragma unroll
    for (int j = 0; j < 4; ++j) {
        const int kk = ty + j * 8;
        Wc[(size_t)(k0 + kk) * H_ + h0 + tx] = tile[tx][kk]; // coalesced along h
    }
}

// ---------------------------------------------------------------------------
// Kernel B: xs GEMM.  out[(b*T+t)*H + h] = bias[h] + sum_i x[b,t,i]*W[h,i]
// M = B*T = 65536, N = H = 512, K = I = 256.  Tile 64x64, BK=32, 256 thr,
// 4x4 accum per thread.  Output written into the outs region of d_out; the
// scan kernel reads it as px and overwrites it with hy.
// ---------------------------------------------------------------------------
__global__ __launch_bounds__(256) void xs_gemm(const float* __restrict__ x,
                                               const float* __restrict__ W,
                                               const float* __restrict__ bias,
                                               float* __restrict__ out) {
    __shared__ float As[64][36];
    __shared__ float Bs[32][64];
    const int m0 = blockIdx.x * 64;
    const int n0 = blockIdx.y * 64;
    const int t  = threadIdx.x;
    const int tm = (t >> 4) << 2;  // 0..60
    const int tn = (t & 15) << 2;  // 0..60
    float acc[4][4] = {};

    for (int k0 = 0; k0 < 256; k0 += 32) {
        {
            const int row = t >> 3;          // 0..31
            const int col = (t & 7) << 2;    // 0,4,..28
            const float4 v0 = *(const float4*)&x[(size_t)(m0 + row) * I_ + k0 + col];
            const float4 v1 = *(const float4*)&x[(size_t)(m0 + row + 32) * I_ + k0 + col];
            *(float4*)&As[row][col]      = v0;
            *(float4*)&As[row + 32][col] = v1;
        }
        {
            const int n  = t >> 2;           // 0..63
            const int kq = (t & 3) << 3;     // 0,8,16,24
            const float4 w0 = *(const float4*)&W[(size_t)(n0 + n) * WS_ + k0 + kq];
            const float4 w1 = *(const float4*)&W[(size_t)(n0 + n) * WS_ + k0 + kq + 4];
            Bs[kq + 0][n] = w0.x; Bs[kq + 1][n] = w0.y;
            Bs[kq + 2][n] = w0.z; Bs[kq + 3][n] = w0.w;
            Bs[kq + 4][n] = w1.x; Bs[kq + 5][n] = w1.y;
            Bs[kq + 6][n] = w1.z; Bs[kq + 7][n] = w1.w;
        }
        __syncthreads();
#pragma unroll
        for (int k = 0; k < 32; ++k) {
            const float a0 = As[tm + 0][k];
            const float a1 = As[tm + 1][k];
            const float a2 = As[tm + 2][k];
            const float a3 = As[tm + 3][k];
            const float4 bv = *(const float4*)&Bs[k][tn];
            acc[0][0] += a0 * bv.x; acc[0][1] += a0 * bv.y; acc[0][2] += a0 * bv.z; acc[0][3] += a0 * bv.w;
            acc[1][0] += a1 * bv.x; acc[1][1] += a1 * bv.y; acc[1][2] += a1 * bv.z; acc[1][3] += a1 * bv.w;
            acc[2][0] += a2 * bv.x; acc[2][1] += a2 * bv.y; acc[2][2] += a2 * bv.z; acc[2][3] += a2 * bv.w;
            acc[3][0] += a3 * bv.x; acc[3][1] += a3 * bv.y; acc[3][2] += a3 * bv.z; acc[3][3] += a3 * bv.w;
        }
        __syncthreads();
    }
#pragma unroll
    for (int r = 0; r < 4; ++r) {
        float4 o;
        o.x = acc[r][0] + bias[n0 + tn + 0];
        o.y = acc[r][1] + bias[n0 + tn + 1];
        o.z = acc[r][2] + bias[n0 + tn + 2];
        o.w = acc[r][3] + bias[n0 + tn + 3];
        *(float4*)&out[(size_t)(m0 + tm + r) * H_ + n0 + tn] = o;
    }
}

// ---------------------------------------------------------------------------
// Kernel C: sequential scan.  One block per batch element (64 blocks),
// 512 threads.  State S = [hz(512) | hy(512)] in LDS; thread t owns h=t.
// Matvec: 4-way K-split, thread (kp, h4) accumulates a float4 of partial
// pre over k in [kp*256, (kp+1)*256).  Weight rows of Wc are contiguous in
// h -> dwordx4 loads, 1KB/wave.  Reduce via LDS, then pointwise update.
// ---------------------------------------------------------------------------
__global__ __launch_bounds__(512) void rnn_scan(const float* __restrict__ Wc,
                                                float* __restrict__ out) {
    __shared__ float S[2 * H_];      // [hz | hy]
    __shared__ float P[4][H_];       // K-split partials
    const int b  = blockIdx.x;
    const int t  = threadIdx.x;
    const int h4 = (t & 127) << 2;   // 0,4,...,508
    const int kp = t >> 7;           // 0..3
    const int kbase = kp << 8;       // kp*256

    float hy = 0.f, hz = 0.f;
    S[t] = 0.f;
    S[H_ + t] = 0.f;
    __syncthreads();

    float* outb = out + (size_t)b * T_ * H_;
    const float* wp = Wc + (size_t)kbase * H_ + h4;

    for (int step = 0; step < T_; ++step) {
        float a0 = 0.f, a1 = 0.f, a2 = 0.f, a3 = 0.f;
#pragma unroll 2
        for (int k = 0; k < 256; k += 4) {
            const float4 s  = *(const float4*)&S[kbase + k];
            const float4 w0 = *(const float4*)&wp[(size_t)(k + 0) * H_];
            const float4 w1 = *(const float4*)&wp[(size_t)(k + 1) * H_];
            const float4 w2 = *(const float4*)&wp[(size_t)(k + 2) * H_];
            const float4 w3 = *(const float4*)&wp[(size_t)(k + 3) * H_];
            a0 += s.x * w0.x; a1 += s.x * w0.y; a2 += s.x * w0.z; a3 += s.x * w0.w;
            a0 += s.y * w1.x; a1 += s.y * w1.y; a2 += s.y * w1.z; a3 += s.y * w1.w;
            a0 += s.z * w2.x; a1 += s.z * w2.y; a2 += s.z * w2.z; a3 += s.z * w2.w;
            a0 += s.w * w3.x; a1 += s.w * w3.y; a2 += s.w * w3.z; a3 += s.w * w3.w;
        }
        *(float4*)&P[kp][h4] = make_float4(a0, a1, a2, a3);
        __syncthreads();

        const float px  = outb[(size_t)step * H_ + t];
        const float pre = px + P[0][t] + P[1][t] + P[2][t] + P[3][t];
        hz = hz + DT_ * (tanhf(pre) - GAMMA_ * hy - EPS_ * hz);
        hy = hy + DT_ * hz;
        outb[(size_t)step * H_ + t] = hy;
        S[t]      = hz;
        S[H_ + t] = hy;
        __syncthreads();
    }
    out[(size_t)B_ * T_ * H_ + (size_t)b * H_ + t] = hy;
}

// ---------------------------------------------------------------------------
extern "C" void kernel_launch(void* const* d_in, const int* in_sizes, int n_in,
                              void* d_out, int out_size, void* d_ws, size_t ws_size,
                              hipStream_t stream) {
    const float* x    = (const float*)d_in[0];
    const float* W    = (const float*)d_in[1];
    const float* bias = (const float*)d_in[2];
    float* out = (float*)d_out;
    float* Wc  = (float*)d_ws;   // 1024 x 512 fp32 = 2 MB scratch

    wtrans_kernel<<<dim3(32, 16), dim3(32, 8), 0, stream>>>(W, Wc);
    xs_gemm<<<dim3(1024, 8), 256, 0, stream>>>(x, W, bias, out);
    rnn_scan<<<64, 512, 0, stream>>>(Wc, out);
}

// Round 3
// 8066.134 us; speedup vs baseline: 1.8845x; 1.8845x over previous
//
#include <hip/hip_runtime.h>
#include <hip/hip_fp16.h>
#include <cmath>

#define DT_     0.054f
#define GAMMA_  4.9f
#define EPS_    4.8f
#define B_      64
#define T_      1024
#define I_      256
#define H_      512
#define WS_     1280          // W row stride = I + 2H
#define KK_     1024          // state dim (hz|hy)
#define KC_     512           // state dim in half2 units
#define NB_     16            // batch groups
#define NH_     8             // h slices
#define BS_     4             // batches per block  (64/NB_)
#define HS_     64            // h per block        (512/NH_)

// d_ws layout
#define WH2_OFF  0                        // half2 weights [512 kc][512 h] = 1 MB
#define CTR_OFF  (1u << 20)               // 16 counters, 64B stride = 1 KB
#define SBUF_OFF ((1u << 20) + 4096)      // state: [2][64 b][512 kc] half2 = 256 KB

// ---------------------------------------------------------------------------
// fdot2 wrapper (v_dot2_f32_f16) with portable fallback
// ---------------------------------------------------------------------------
typedef _Float16 half2_t __attribute__((ext_vector_type(2)));
static __device__ __forceinline__ float dot2f(__half2 a, __half2 b, float c) {
#if defined(__has_builtin)
#if __has_builtin(__builtin_amdgcn_fdot2)
    return __builtin_amdgcn_fdot2(*(half2_t*)&a, *(half2_t*)&b, c, false);
#else
    float2 fa = __half22float2(a), fb = __half22float2(b);
    return fmaf(fa.y, fb.y, fmaf(fa.x, fb.x, c));
#endif
#else
    float2 fa = __half22float2(a), fb = __half22float2(b);
    return fmaf(fa.y, fb.y, fmaf(fa.x, fb.x, c));
#endif
}

// ---------------------------------------------------------------------------
// Kernel A: W[:, 256:1280] -> f16 half2 Wh2[kc][h], half2 = {WT[2kc][h], WT[2kc+1][h]}
// where WT[k][h] = W[h][256+k].  Coalesced both sides via LDS tile.
// ---------------------------------------------------------------------------
__global__ __launch_bounds__(256) void wtrans_f16(const float* __restrict__ W,
                                                  __half2* __restrict__ Wh2) {
    __shared__ float tile[32][33];        // [h-local][k-local]
    const int k0 = blockIdx.x * 32;       // k tile (32 k = 16 kc)
    const int h0 = blockIdx.y * 32;
    const int tx = threadIdx.x;           // 0..31
    const int ty = threadIdx.y;           // 0..7
#pragma unroll
    for (int j = 0; j < 4; ++j) {
        const int hh = ty + j * 8;
        tile[hh][tx] = W[(size_t)(h0 + hh) * WS_ + 256 + k0 + tx];  // coalesced in k
    }
    __syncthreads();
#pragma unroll
    for (int j = 0; j < 2; ++j) {
        const int kcl = ty + j * 8;       // 0..15
        const int kc  = (k0 >> 1) + kcl;
        const __half2 v = __floats2half2_rn(tile[tx][2 * kcl], tile[tx][2 * kcl + 1]);
        Wh2[(size_t)kc * H_ + h0 + tx] = v;   // coalesced in h
    }
}

// ---------------------------------------------------------------------------
// Kernel B: xs GEMM (unchanged): out[(b*T+t)*H+h] = bias[h] + sum_i x*Wx
// ---------------------------------------------------------------------------
__global__ __launch_bounds__(256) void xs_gemm(const float* __restrict__ x,
                                               const float* __restrict__ W,
                                               const float* __restrict__ bias,
                                               float* __restrict__ out) {
    __shared__ float As[64][36];
    __shared__ float Bs[32][64];
    const int m0 = blockIdx.x * 64;
    const int n0 = blockIdx.y * 64;
    const int t  = threadIdx.x;
    const int tm = (t >> 4) << 2;
    const int tn = (t & 15) << 2;
    float acc[4][4] = {};

    for (int k0 = 0; k0 < 256; k0 += 32) {
        {
            const int row = t >> 3;
            const int col = (t & 7) << 2;
            const float4 v0 = *(const float4*)&x[(size_t)(m0 + row) * I_ + k0 + col];
            const float4 v1 = *(const float4*)&x[(size_t)(m0 + row + 32) * I_ + k0 + col];
            *(float4*)&As[row][col]      = v0;
            *(float4*)&As[row + 32][col] = v1;
        }
        {
            const int n  = t >> 2;
            const int kq = (t & 3) << 3;
            const float4 w0 = *(const float4*)&W[(size_t)(n0 + n) * WS_ + k0 + kq];
            const float4 w1 = *(const float4*)&W[(size_t)(n0 + n) * WS_ + k0 + kq + 4];
            Bs[kq + 0][n] = w0.x; Bs[kq + 1][n] = w0.y;
            Bs[kq + 2][n] = w0.z; Bs[kq + 3][n] = w0.w;
            Bs[kq + 4][n] = w1.x; Bs[kq + 5][n] = w1.y;
            Bs[kq + 6][n] = w1.z; Bs[kq + 7][n] = w1.w;
        }
        __syncthreads();
#pragma unroll
        for (int k = 0; k < 32; ++k) {
            const float a0 = As[tm + 0][k];
            const float a1 = As[tm + 1][k];
            const float a2 = As[tm + 2][k];
            const float a3 = As[tm + 3][k];
            const float4 bv = *(const float4*)&Bs[k][tn];
            acc[0][0] += a0 * bv.x; acc[0][1] += a0 * bv.y; acc[0][2] += a0 * bv.z; acc[0][3] += a0 * bv.w;
            acc[1][0] += a1 * bv.x; acc[1][1] += a1 * bv.y; acc[1][2] += a1 * bv.z; acc[1][3] += a1 * bv.w;
            acc[2][0] += a2 * bv.x; acc[2][1] += a2 * bv.y; acc[2][2] += a2 * bv.z; acc[2][3] += a2 * bv.w;
            acc[3][0] += a3 * bv.x; acc[3][1] += a3 * bv.y; acc[3][2] += a3 * bv.z; acc[3][3] += a3 * bv.w;
        }
        __syncthreads();
    }
#pragma unroll
    for (int r = 0; r < 4; ++r) {
        float4 o;
        o.x = acc[r][0] + bias[n0 + tn + 0];
        o.y = acc[r][1] + bias[n0 + tn + 1];
        o.z = acc[r][2] + bias[n0 + tn + 2];
        o.w = acc[r][3] + bias[n0 + tn + 3];
        *(float4*)&out[(size_t)(m0 + tm + r) * H_ + n0 + tn] = o;
    }
}

// ---------------------------------------------------------------------------
// Kernel C: scan with LDS-resident f16 weight slices + inter-block exchange.
// 128 blocks = NB_(16 batch groups) x NH_(8 h-slices), 512 threads.
// Block (bb,hb): weights WT[k][h0..h0+64) live in LDS (128 KB f16).
// Owners: threads 0..255 hold fp32 (hy,hz) for (4 b x 64 h).
// Per step: stage f16 state (4 b x 1024 k, 8 KB) -> LDS, dot2 matvec,
// reduce over 8 kp waves, pointwise update, write f16 state + fp32 out,
// device-scope group barrier among the 8 h-blocks of this batch group.
// ---------------------------------------------------------------------------
union U4H { uint4 u; __half2 h[4]; };

__global__ __launch_bounds__(512) void rnn_scan(const __half2* __restrict__ Wh2,
                                                __half2* __restrict__ Sbuf,
                                                unsigned* __restrict__ ctr,
                                                float* __restrict__ out) {
    __shared__ __align__(16) __half2 Wl[KC_ / 4][HS_][4];  // 128 KB
    __shared__ __align__(16) __half2 Sl[BS_][KC_];         // 8 KB
    __shared__ float P[NH_][BS_][HS_];                     // 8 KB

    const int bid = blockIdx.x;
    const int bb  = bid >> 3;          // batch group 0..15
    const int hb  = bid & 7;           // h slice    0..7
    const int tid = threadIdx.x;
    const int h   = tid & 63;
    const int kp  = tid >> 6;          // wave id 0..7
    const int h0  = hb * HS_;

    // ---- load weight slice into LDS (one-time) ----
    for (int i = tid; i < KC_ * HS_; i += 512) {
        const int kc = i >> 6;
        const int hh = i & 63;
        Wl[kc >> 2][hh][kc & 3] = Wh2[(size_t)kc * H_ + h0 + hh];
    }

    // owner mapping (tid < 256): b-own = tid>>6, h-own = tid&63
    const int bown  = (tid >> 6) & 3;
    const int hown  = tid & 63;
    const int bglob = bb * BS_ + bown;
    float* outp = out + (size_t)bglob * T_ * H_ + h0 + hown;   // + step*H_
    float hy = 0.f, hz = 0.f;

    unsigned target = NH_;
    __syncthreads();   // Wl ready

    for (int step = 0; step < T_; ++step) {
        // prefetch px early (hides HBM latency under the matvec)
        float px = 0.f;
        if (tid < 256) px = outp[(size_t)step * H_];

        if (step > 0) {
            // ---- stage state for this batch group: 512 x uint4 = 8 KB ----
            const uint4* g = (const uint4*)(Sbuf + ((size_t)(step & 1) * B_ + bb * BS_) * KC_);
            ((uint4*)&Sl[0][0])[tid] = g[tid];
            __syncthreads();

            // ---- dot2 matvec: this wave covers kc in [kp*64, kp*64+64) ----
            float acc[4] = {0.f, 0.f, 0.f, 0.f};
#pragma unroll
            for (int q = 0; q < 16; ++q) {
                const int kc4 = kp * 16 + q;
                U4H w; w.u = *(const uint4*)&Wl[kc4][h][0];
#pragma unroll
                for (int b = 0; b < 4; ++b) {
                    U4H s; s.u = *(const uint4*)&Sl[b][kc4 << 2];
                    acc[b] = dot2f(w.h[0], s.h[0], acc[b]);
                    acc[b] = dot2f(w.h[1], s.h[1], acc[b]);
                    acc[b] = dot2f(w.h[2], s.h[2], acc[b]);
                    acc[b] = dot2f(w.h[3], s.h[3], acc[b]);
                }
            }
#pragma unroll
            for (int b = 0; b < 4; ++b) P[kp][b][h] = acc[b];
            __syncthreads();
        }

        // ---- owner update ----
        if (tid < 256) {
            float pre = px;
            if (step > 0) {
#pragma unroll
                for (int k2 = 0; k2 < NH_; ++k2) pre += P[k2][bown][hown];
            }
            hz = hz + DT_ * (tanhf(pre) - GAMMA_ * hy - EPS_ * hz);
            hy = hy + DT_ * hz;
            outp[(size_t)step * H_] = hy;
            // publish f16 state for next step
            __half* s16 = (__half*)Sbuf + ((size_t)(((step + 1) & 1)) * B_ + bglob) * KK_;
            s16[h0 + hown]        = __float2half(hz);   // k = h_global
            s16[512 + h0 + hown]  = __float2half(hy);   // k = 512 + h_global
        }

        // ---- device-scope group barrier (8 blocks sharing bb) ----
        __syncthreads();
        if (tid == 0) {
            __threadfence();   // flush state stores to agent scope
            __hip_atomic_fetch_add(&ctr[bb * 16], 1u, __ATOMIC_RELAXED, __HIP_MEMORY_SCOPE_AGENT);
            while (__hip_atomic_load(&ctr[bb * 16], __ATOMIC_RELAXED, __HIP_MEMORY_SCOPE_AGENT) < target) {}
            target += NH_;
            __threadfence();   // invalidate stale cached state
        }
        __syncthreads();
    }

    if (tid < 256) {
        out[(size_t)B_ * T_ * H_ + (size_t)bglob * H_ + h0 + hown] = hy;
    }
}

// ---------------------------------------------------------------------------
extern "C" void kernel_launch(void* const* d_in, const int* in_sizes, int n_in,
                              void* d_out, int out_size, void* d_ws, size_t ws_size,
                              hipStream_t stream) {
    const float* x    = (const float*)d_in[0];
    const float* W    = (const float*)d_in[1];
    const float* bias = (const float*)d_in[2];
    float* out = (float*)d_out;

    __half2*  Wh2  = (__half2*)((char*)d_ws + WH2_OFF);
    unsigned* ctr  = (unsigned*)((char*)d_ws + CTR_OFF);
    __half2*  Sbuf = (__half2*)((char*)d_ws + SBUF_OFF);

    hipMemsetAsync((char*)d_ws + CTR_OFF, 0, 4096, stream);
    wtrans_f16<<<dim3(32, 16), dim3(32, 8), 0, stream>>>(W, Wh2);
    xs_gemm<<<dim3(1024, 8), 256, 0, stream>>>(x, W, bias, out);
    rnn_scan<<<NB_ * NH_, 512, 0, stream>>>(Wh2, Sbuf, ctr, out);
}

// Round 4
// 3785.580 us; speedup vs baseline: 4.0153x; 2.1308x over previous
//
#include <hip/hip_runtime.h>
#include <hip/hip_fp16.h>
#include <cmath>

#define DT_     0.054f
#define GAMMA_  4.9f
#define EPS_    4.8f
#define B_      64
#define T_      1024
#define I_      256
#define H_      512
#define WS_     1280          // W row stride = I + 2H
#define NB_     16            // batch groups
#define NH_     8             // h slices (blocks per group)
#define BS_     4             // batches per block
#define HS_     64            // h per block

// d_ws layout
#define WP_OFF   0                        // half2 Wp[512 c][512 h] = 1 MB
#define CTR_OFF  (1u << 20)               // 16 counters, 64B stride
#define SBUF_OFF ((1u << 20) + 4096)      // u32 state [2][64 b][512 c] = 256 KB

// ---------------------------------------------------------------------------
typedef _Float16 half2_t __attribute__((ext_vector_type(2)));
static __device__ __forceinline__ float dot2f(__half2 a, __half2 b, float c) {
#if defined(__has_builtin)
#if __has_builtin(__builtin_amdgcn_fdot2)
    return __builtin_amdgcn_fdot2(*(half2_t*)&a, *(half2_t*)&b, c, false);
#else
    float2 fa = __half22float2(a), fb = __half22float2(b);
    return fmaf(fa.y, fb.y, fmaf(fa.x, fb.x, c));
#endif
#else
    float2 fa = __half22float2(a), fb = __half22float2(b);
    return fmaf(fa.y, fb.y, fmaf(fa.x, fb.x, c));
#endif
}

union U4H { uint4 u; __half2 h[4]; };

// ---------------------------------------------------------------------------
// Kernel A: pack W -> Wp[c][h] = half2( Wz[h][c], Wy[h][c] ), c in [0,512).
// Wz[h][c] = W[h*WS_ + 256 + c], Wy[h][c] = W[h*WS_ + 768 + c].
// So dot2(Wp[c][h], (hz[c],hy[c])) = Wz*hz + Wy*hy.  Coalesced via LDS tiles.
// ---------------------------------------------------------------------------
__global__ __launch_bounds__(256) void wtrans_pack(const float* __restrict__ W,
                                                   __half2* __restrict__ Wp) {
    __shared__ float tz[32][33];
    __shared__ float tyy[32][33];
    const int c0 = blockIdx.x * 32;
    const int h0 = blockIdx.y * 32;
    const int tx = threadIdx.x;   // 0..31
    const int ty = threadIdx.y;   // 0..7
#pragma unroll
    for (int j = 0; j < 4; ++j) {
        const int hh = ty + j * 8;
        tz[hh][tx]  = W[(size_t)(h0 + hh) * WS_ + 256 + c0 + tx];
        tyy[hh][tx] = W[(size_t)(h0 + hh) * WS_ + 768 + c0 + tx];
    }
    __syncthreads();
#pragma unroll
    for (int j = 0; j < 4; ++j) {
        const int cc = ty + j * 8;
        Wp[(size_t)(c0 + cc) * H_ + h0 + tx] = __floats2half2_rn(tz[tx][cc], tyy[tx][cc]);
    }
}

// ---------------------------------------------------------------------------
// Kernel B: xs GEMM (unchanged, verified): out[(b*T+t)*H+h] = bias[h] + x.Wx
// ---------------------------------------------------------------------------
__global__ __launch_bounds__(256) void xs_gemm(const float* __restrict__ x,
                                               const float* __restrict__ W,
                                               const float* __restrict__ bias,
                                               float* __restrict__ out) {
    __shared__ float As[64][36];
    __shared__ float Bs[32][64];
    const int m0 = blockIdx.x * 64;
    const int n0 = blockIdx.y * 64;
    const int t  = threadIdx.x;
    const int tm = (t >> 4) << 2;
    const int tn = (t & 15) << 2;
    float acc[4][4] = {};

    for (int k0 = 0; k0 < 256; k0 += 32) {
        {
            const int row = t >> 3;
            const int col = (t & 7) << 2;
            const float4 v0 = *(const float4*)&x[(size_t)(m0 + row) * I_ + k0 + col];
            const float4 v1 = *(const float4*)&x[(size_t)(m0 + row + 32) * I_ + k0 + col];
            *(float4*)&As[row][col]      = v0;
            *(float4*)&As[row + 32][col] = v1;
        }
        {
            const int n  = t >> 2;
            const int kq = (t & 3) << 3;
            const float4 w0 = *(const float4*)&W[(size_t)(n0 + n) * WS_ + k0 + kq];
            const float4 w1 = *(const float4*)&W[(size_t)(n0 + n) * WS_ + k0 + kq + 4];
            Bs[kq + 0][n] = w0.x; Bs[kq + 1][n] = w0.y;
            Bs[kq + 2][n] = w0.z; Bs[kq + 3][n] = w0.w;
            Bs[kq + 4][n] = w1.x; Bs[kq + 5][n] = w1.y;
            Bs[kq + 6][n] = w1.z; Bs[kq + 7][n] = w1.w;
        }
        __syncthreads();
#pragma unroll
        for (int k = 0; k < 32; ++k) {
            const float a0 = As[tm + 0][k];
            const float a1 = As[tm + 1][k];
            const float a2 = As[tm + 2][k];
            const float a3 = As[tm + 3][k];
            const float4 bv = *(const float4*)&Bs[k][tn];
            acc[0][0] += a0 * bv.x; acc[0][1] += a0 * bv.y; acc[0][2] += a0 * bv.z; acc[0][3] += a0 * bv.w;
            acc[1][0] += a1 * bv.x; acc[1][1] += a1 * bv.y; acc[1][2] += a1 * bv.z; acc[1][3] += a1 * bv.w;
            acc[2][0] += a2 * bv.x; acc[2][1] += a2 * bv.y; acc[2][2] += a2 * bv.z; acc[2][3] += a2 * bv.w;
            acc[3][0] += a3 * bv.x; acc[3][1] += a3 * bv.y; acc[3][2] += a3 * bv.z; acc[3][3] += a3 * bv.w;
        }
        __syncthreads();
    }
#pragma unroll
    for (int r = 0; r < 4; ++r) {
        float4 o;
        o.x = acc[r][0] + bias[n0 + tn + 0];
        o.y = acc[r][1] + bias[n0 + tn + 1];
        o.z = acc[r][2] + bias[n0 + tn + 2];
        o.w = acc[r][3] + bias[n0 + tn + 3];
        *(float4*)&out[(size_t)(m0 + tm + r) * H_ + n0 + tn] = o;
    }
}

// ---------------------------------------------------------------------------
// Kernel C: scan.  128 blocks = 16 batch groups x 8 h-slices, 512 threads.
// LDS-resident f16 weight slice (128 KB).  State element c = half2(hz[c],hy[c])
// published as ONE u32 relaxed agent-scope atomic store (write-through to the
// coherence point -> no threadfence / L2 writeback on the critical path).
// Readers stage with relaxed agent-scope 64-bit atomic loads (bypass L1/L2).
// Group barrier: relaxed fetch_add + relaxed spin; __syncthreads drains
// vmcnt(0) before the master arrives, so state is visible before the count.
// ---------------------------------------------------------------------------
__global__ __launch_bounds__(512) void rnn_scan(const __half2* __restrict__ Wp,
                                                unsigned* __restrict__ Sbuf,
                                                unsigned* __restrict__ ctr,
                                                float* __restrict__ out) {
    __shared__ __align__(16) __half2 Wl[128][HS_][4];   // [c4][h][c&3], 128 KB
    __shared__ __align__(16) unsigned Sl[BS_][H_];      // [b][c] half2-as-u32, 8 KB
    __shared__ float P[NH_][BS_][HS_];                  // 8 KB

    const int bid = blockIdx.x;
    const int bb  = bid >> 3;          // batch group 0..15
    const int hb  = bid & 7;           // h slice    0..7
    const int tid = threadIdx.x;
    const int h   = tid & 63;
    const int kp  = tid >> 6;          // wave id 0..7
    const int h0  = hb * HS_;

    // one-time: weight slice into LDS (coalesced: consecutive tid -> consecutive h)
    for (int i = tid; i < H_ * HS_; i += 512) {
        const int c  = i >> 6;
        const int hh = i & 63;
        Wl[c >> 2][hh][c & 3] = Wp[(size_t)c * H_ + h0 + hh];
    }

    const int bown  = (tid >> 6) & 3;
    const int hown  = tid & 63;
    const int bglob = bb * BS_ + bown;
    const int cg    = h0 + hown;               // owner's state index
    float* outp = out + (size_t)bglob * T_ * H_ + h0 + hown;
    float hy = 0.f, hz = 0.f;
    float px = 0.f;
    if (tid < 256) px = outp[0];

    unsigned target = NH_;
    __syncthreads();   // Wl ready

    for (int step = 0; step < T_; ++step) {
        if (step > 0) {
            // ---- stage group state: 8 KB via 64-bit agent-scope loads ----
            unsigned long long* g = (unsigned long long*)
                (Sbuf + ((size_t)(step & 1) * B_ + bb * BS_) * H_);
            const unsigned long long v0 =
                __hip_atomic_load(&g[tid], __ATOMIC_RELAXED, __HIP_MEMORY_SCOPE_AGENT);
            const unsigned long long v1 =
                __hip_atomic_load(&g[tid + 512], __ATOMIC_RELAXED, __HIP_MEMORY_SCOPE_AGENT);
            ((unsigned long long*)&Sl[0][0])[tid]       = v0;
            ((unsigned long long*)&Sl[0][0])[tid + 512] = v1;
            __syncthreads();

            // ---- dot2 matvec: wave kp covers c4 in [kp*16, kp*16+16) ----
            float acc[4] = {0.f, 0.f, 0.f, 0.f};
#pragma unroll
            for (int q = 0; q < 16; ++q) {
                const int c4 = kp * 16 + q;
                U4H w; w.u = *(const uint4*)&Wl[c4][h][0];
#pragma unroll
                for (int b = 0; b < 4; ++b) {
                    U4H s; s.u = *(const uint4*)&Sl[b][c4 << 2];
                    acc[b] = dot2f(w.h[0], s.h[0], acc[b]);
                    acc[b] = dot2f(w.h[1], s.h[1], acc[b]);
                    acc[b] = dot2f(w.h[2], s.h[2], acc[b]);
                    acc[b] = dot2f(w.h[3], s.h[3], acc[b]);
                }
            }
#pragma unroll
            for (int b = 0; b < 4; ++b) P[kp][b][h] = acc[b];
            __syncthreads();
        }

        // ---- owner update ----
        if (tid < 256) {
            float pre = px;
            if (step > 0) {
#pragma unroll
                for (int k2 = 0; k2 < NH_; ++k2) pre += P[k2][bown][hown];
            }
            hz = hz + DT_ * (tanhf(pre) - GAMMA_ * hy - EPS_ * hz);
            hy = hy + DT_ * hz;
            outp[(size_t)step * H_] = hy;
            if (step + 1 < T_) {
                px = outp[(size_t)(step + 1) * H_];   // prefetch before barrier
                const __half2 st = __floats2half2_rn(hz, hy);
                __hip_atomic_store(&Sbuf[((size_t)((step + 1) & 1) * B_ + bglob) * H_ + cg],
                                   *(const unsigned*)&st,
                                   __ATOMIC_RELAXED, __HIP_MEMORY_SCOPE_AGENT);
            }
        }

        // ---- group barrier (8 blocks of batch group bb) ----
        if (step + 1 < T_) {
            __syncthreads();   // drains vmcnt(0): state stores at coherence point
            if (tid == 0) {
                __hip_atomic_fetch_add(&ctr[bb * 16], 1u,
                                       __ATOMIC_RELAXED, __HIP_MEMORY_SCOPE_AGENT);
                while (__hip_atomic_load(&ctr[bb * 16],
                                         __ATOMIC_RELAXED, __HIP_MEMORY_SCOPE_AGENT) < target) {}
                target += NH_;
            }
            __syncthreads();
        }
    }

    if (tid < 256) {
        out[(size_t)B_ * T_ * H_ + (size_t)bglob * H_ + h0 + hown] = hy;
    }
}

// ---------------------------------------------------------------------------
extern "C" void kernel_launch(void* const* d_in, const int* in_sizes, int n_in,
                              void* d_out, int out_size, void* d_ws, size_t ws_size,
                              hipStream_t stream) {
    const float* x    = (const float*)d_in[0];
    const float* W    = (const float*)d_in[1];
    const float* bias = (const float*)d_in[2];
    float* out = (float*)d_out;

    __half2*  Wp   = (__half2*)((char*)d_ws + WP_OFF);
    unsigned* ctr  = (unsigned*)((char*)d_ws + CTR_OFF);
    unsigned* Sbuf = (unsigned*)((char*)d_ws + SBUF_OFF);

    hipMemsetAsync((char*)d_ws + CTR_OFF, 0, 4096, stream);
    wtrans_pack<<<dim3(16, 16), dim3(32, 8), 0, stream>>>(W, Wp);
    xs_gemm<<<dim3(1024, 8), 256, 0, stream>>>(x, W, bias, out);
    rnn_scan<<<NB_ * NH_, 512, 0, stream>>>(Wp, Sbuf, ctr, out);
}

// Round 7
// 2924.526 us; speedup vs baseline: 5.1976x; 1.2944x over previous
//
#include <hip/hip_runtime.h>
#include <hip/hip_fp16.h>
#include <cmath>

#define DT_     0.054f
#define GAMMA_  4.9f
#define EPS_    4.8f
#define B_      64
#define T_      1024
#define I_      256
#define H_      512
#define WS_     1280          // W row stride = I + 2H
#define NB_     16            // batch groups
#define NH_     8             // h slices (blocks per group)
#define BS_     4             // batches per block
#define HS_     64            // h per block

// d_ws layout
#define WP_OFF   0                        // half2 Wp[512 c][512 h] = 1 MB
#define CTR_OFF  (1u << 20)               // 16 counters, 64B stride
#define SBUF_OFF ((1u << 20) + 4096)      // u32 state [2][64 b][512 c] = 256 KB

typedef _Float16 f16x8 __attribute__((ext_vector_type(8)));
typedef float    f32x4 __attribute__((ext_vector_type(4)));
union AFrag { unsigned long long q[2]; unsigned u[4]; f16x8 v; };

// ---------------------------------------------------------------------------
// Kernel A: pack W -> Wp[c][h] = half2( Wz[h][c], Wy[h][c] ), c in [0,512).
// Interleaved-k view: k=2c -> Wz (pairs with hz), k=2c+1 -> Wy (pairs with hy).
// ---------------------------------------------------------------------------
__global__ __launch_bounds__(256) void wtrans_pack(const float* __restrict__ W,
                                                   __half2* __restrict__ Wp) {
    __shared__ float tz[32][33];
    __shared__ float tyy[32][33];
    const int c0 = blockIdx.x * 32;
    const int h0 = blockIdx.y * 32;
    const int tx = threadIdx.x;   // 0..31
    const int ty = threadIdx.y;   // 0..7
#pragma unroll
    for (int j = 0; j < 4; ++j) {
        const int hh = ty + j * 8;
        tz[hh][tx]  = W[(size_t)(h0 + hh) * WS_ + 256 + c0 + tx];
        tyy[hh][tx] = W[(size_t)(h0 + hh) * WS_ + 768 + c0 + tx];
    }
    __syncthreads();
#pragma unroll
    for (int j = 0; j < 4; ++j) {
        const int cc = ty + j * 8;
        Wp[(size_t)(c0 + cc) * H_ + h0 + tx] = __floats2half2_rn(tz[tx][cc], tyy[tx][cc]);
    }
}

// ---------------------------------------------------------------------------
// Kernel B: xs GEMM (unchanged, verified)
// ---------------------------------------------------------------------------
__global__ __launch_bounds__(256) void xs_gemm(const float* __restrict__ x,
                                               const float* __restrict__ W,
                                               const float* __restrict__ bias,
                                               float* __restrict__ out) {
    __shared__ float As[64][36];
    __shared__ float Bs[32][64];
    const int m0 = blockIdx.x * 64;
    const int n0 = blockIdx.y * 64;
    const int t  = threadIdx.x;
    const int tm = (t >> 4) << 2;
    const int tn = (t & 15) << 2;
    float acc[4][4] = {};

    for (int k0 = 0; k0 < 256; k0 += 32) {
        {
            const int row = t >> 3;
            const int col = (t & 7) << 2;
            const float4 v0 = *(const float4*)&x[(size_t)(m0 + row) * I_ + k0 + col];
            const float4 v1 = *(const float4*)&x[(size_t)(m0 + row + 32) * I_ + k0 + col];
            *(float4*)&As[row][col]      = v0;
            *(float4*)&As[row + 32][col] = v1;
        }
        {
            const int n  = t >> 2;
            const int kq = (t & 3) << 3;
            const float4 w0 = *(const float4*)&W[(size_t)(n0 + n) * WS_ + k0 + kq];
            const float4 w1 = *(const float4*)&W[(size_t)(n0 + n) * WS_ + k0 + kq + 4];
            Bs[kq + 0][n] = w0.x; Bs[kq + 1][n] = w0.y;
            Bs[kq + 2][n] = w0.z; Bs[kq + 3][n] = w0.w;
            Bs[kq + 4][n] = w1.x; Bs[kq + 5][n] = w1.y;
            Bs[kq + 6][n] = w1.z; Bs[kq + 7][n] = w1.w;
        }
        __syncthreads();
#pragma unroll
        for (int k = 0; k < 32; ++k) {
            const float a0 = As[tm + 0][k];
            const float a1 = As[tm + 1][k];
            const float a2 = As[tm + 2][k];
            const float a3 = As[tm + 3][k];
            const float4 bv = *(const float4*)&Bs[k][tn];
            acc[0][0] += a0 * bv.x; acc[0][1] += a0 * bv.y; acc[0][2] += a0 * bv.z; acc[0][3] += a0 * bv.w;
            acc[1][0] += a1 * bv.x; acc[1][1] += a1 * bv.y; acc[1][2] += a1 * bv.z; acc[1][3] += a1 * bv.w;
            acc[2][0] += a2 * bv.x; acc[2][1] += a2 * bv.y; acc[2][2] += a2 * bv.z; acc[2][3] += a2 * bv.w;
            acc[3][0] += a3 * bv.x; acc[3][1] += a3 * bv.y; acc[3][2] += a3 * bv.z; acc[3][3] += a3 * bv.w;
        }
        __syncthreads();
    }
#pragma unroll
    for (int r = 0; r < 4; ++r) {
        float4 o;
        o.x = acc[r][0] + bias[n0 + tn + 0];
        o.y = acc[r][1] + bias[n0 + tn + 1];
        o.z = acc[r][2] + bias[n0 + tn + 2];
        o.w = acc[r][3] + bias[n0 + tn + 3];
        *(float4*)&out[(size_t)(m0 + tm + r) * H_ + n0 + tn] = o;
    }
}

// ---------------------------------------------------------------------------
// Kernel C: MFMA scan.  128 blocks = 16 groups x 8 h-slices, 512 thr (8 waves).
// Weights live in VGPRs as B-frags (64 VGPR/thread, loaded once).
// Wave kp covers interleaved-k range [kp*128,(kp+1)*128): per step
//   4 A-frags (state, rows=batch 0..3, loaded via 8 x b64 agent atomic loads)
//   16 x mfma_f32_16x16x32_f16 -> D[b][h] in lanes 0..15, reg=b
//   4 x ds_write_b128 partials -> P[kp][h][b]; owners sum 8 partials.
// Exchange protocol identical to round 4 (relaxed agent atomics + counter).
// ---------------------------------------------------------------------------
__global__ __launch_bounds__(512) void rnn_scan(const __half2* __restrict__ Wp,
                                                unsigned* __restrict__ Sbuf,
                                                unsigned* __restrict__ ctr,
                                                float* __restrict__ out) {
    __shared__ float P[NH_][HS_][4];   // [kp][h_local][b]  8 KB

    const int bid  = blockIdx.x;
    const int bb   = bid >> 3;          // batch group 0..15
    const int hb   = bid & 7;           // h slice    0..7
    const int tid  = threadIdx.x;
    const int kp   = tid >> 6;          // wave 0..7 -> k-range [kp*128, kp*128+128)
    const int lane = tid & 63;
    const int lrow = lane & 15;         // A-row (batch) / B-col (h in tile)
    const int lkg  = lane >> 4;         // k-group 0..3 (8 k each)
    const int h0   = hb * HS_;

    // ---- one-time: weight B-frags into registers (64 VGPR) ----
    // frag[ht][ks] reg r = Wp[c0+r][h0+ht*16+lrow], c0 = kp*64 + ks*16 + 4*lkg
    AFrag bw[4][4];
#pragma unroll
    for (int ht = 0; ht < 4; ++ht) {
#pragma unroll
        for (int ks = 0; ks < 4; ++ks) {
            const int c0 = kp * 64 + ks * 16 + 4 * lkg;
            const int h  = h0 + ht * 16 + lrow;
#pragma unroll
            for (int r = 0; r < 4; ++r)
                bw[ht][ks].u[r] = *(const unsigned*)&Wp[(size_t)(c0 + r) * H_ + h];
        }
    }

    const int bown  = (tid >> 6) & 3;
    const int hown  = tid & 63;
    const int bglob = bb * BS_ + bown;
    const int cg    = h0 + hown;
    float* outp = out + (size_t)bglob * T_ * H_ + h0 + hown;
    float hy = 0.f, hz = 0.f, px = 0.f;
    if (tid < 256) px = outp[0];

    unsigned target = NH_;
    __syncthreads();

    for (int step = 0; step < T_; ++step) {
        if (step > 0) {
            // ---- A-frags: state rows 0..3, 8 contiguous interleaved-k halves ----
            AFrag af0, af1, af2, af3;
            if (lrow < 4) {
                const unsigned long long* sb = (const unsigned long long*)
                    (Sbuf + ((size_t)(step & 1) * B_ + (bb * BS_ + lrow)) * H_);
                const int qi = kp * 32 + 2 * lkg;   // u64 index; +ks*8 per k-step
                af0.q[0] = __hip_atomic_load(&sb[qi +  0], __ATOMIC_RELAXED, __HIP_MEMORY_SCOPE_AGENT);
                af0.q[1] = __hip_atomic_load(&sb[qi +  1], __ATOMIC_RELAXED, __HIP_MEMORY_SCOPE_AGENT);
                af1.q[0] = __hip_atomic_load(&sb[qi +  8], __ATOMIC_RELAXED, __HIP_MEMORY_SCOPE_AGENT);
                af1.q[1] = __hip_atomic_load(&sb[qi +  9], __ATOMIC_RELAXED, __HIP_MEMORY_SCOPE_AGENT);
                af2.q[0] = __hip_atomic_load(&sb[qi + 16], __ATOMIC_RELAXED, __HIP_MEMORY_SCOPE_AGENT);
                af2.q[1] = __hip_atomic_load(&sb[qi + 17], __ATOMIC_RELAXED, __HIP_MEMORY_SCOPE_AGENT);
                af3.q[0] = __hip_atomic_load(&sb[qi + 24], __ATOMIC_RELAXED, __HIP_MEMORY_SCOPE_AGENT);
                af3.q[1] = __hip_atomic_load(&sb[qi + 25], __ATOMIC_RELAXED, __HIP_MEMORY_SCOPE_AGENT);
            } else {
                af0.q[0] = af0.q[1] = 0ull; af1 = af0; af2 = af0; af3 = af0;
            }

            f32x4 acc0 = {0.f, 0.f, 0.f, 0.f};
            f32x4 acc1 = acc0, acc2 = acc0, acc3 = acc0;
#pragma unroll
            for (int ks = 0; ks < 4; ++ks) {
                const f16x8 a = (ks == 0) ? af0.v : (ks == 1) ? af1.v : (ks == 2) ? af2.v : af3.v;
                acc0 = __builtin_amdgcn_mfma_f32_16x16x32_f16(a, bw[0][ks].v, acc0, 0, 0, 0);
                acc1 = __builtin_amdgcn_mfma_f32_16x16x32_f16(a, bw[1][ks].v, acc1, 0, 0, 0);
                acc2 = __builtin_amdgcn_mfma_f32_16x16x32_f16(a, bw[2][ks].v, acc2, 0, 0, 0);
                acc3 = __builtin_amdgcn_mfma_f32_16x16x32_f16(a, bw[3][ks].v, acc3, 0, 0, 0);
            }
            if (lane < 16) {   // rows(b)=reg 0..3, col(h)=lane
                *(f32x4*)&P[kp][ 0 + lane][0] = acc0;
                *(f32x4*)&P[kp][16 + lane][0] = acc1;
                *(f32x4*)&P[kp][32 + lane][0] = acc2;
                *(f32x4*)&P[kp][48 + lane][0] = acc3;
            }
        }
        __syncthreads();

        // ---- owner update: thread t<256 owns (bown, hown) ----
        if (tid < 256) {
            float pre = px;
            if (step > 0) {
#pragma unroll
                for (int k2 = 0; k2 < NH_; ++k2) pre += P[k2][hown][bown];
            }
            hz = hz + DT_ * (tanhf(pre) - GAMMA_ * hy - EPS_ * hz);
            hy = hy + DT_ * hz;
            outp[(size_t)step * H_] = hy;
            if (step + 1 < T_) {
                px = outp[(size_t)(step + 1) * H_];   // prefetch before barrier
                const __half2 st = __floats2half2_rn(hz, hy);
                __hip_atomic_store(&Sbuf[((size_t)((step + 1) & 1) * B_ + bglob) * H_ + cg],
                                   *(const unsigned*)&st,
                                   __ATOMIC_RELAXED, __HIP_MEMORY_SCOPE_AGENT);
            }
        }

        // ---- group barrier (8 h-blocks of batch group bb) ----
        if (step + 1 < T_) {
            __syncthreads();   // drains vmcnt(0): state stores at coherence point
            if (tid == 0) {
                __hip_atomic_fetch_add(&ctr[bb * 16], 1u,
                                       __ATOMIC_RELAXED, __HIP_MEMORY_SCOPE_AGENT);
                while (__hip_atomic_load(&ctr[bb * 16],
                                         __ATOMIC_RELAXED, __HIP_MEMORY_SCOPE_AGENT) < target) {}
                target += NH_;
            }
            __syncthreads();
        }
    }

    if (tid < 256) {
        out[(size_t)B_ * T_ * H_ + (size_t)bglob * H_ + h0 + hown] = hy;
    }
}

// ---------------------------------------------------------------------------
extern "C" void kernel_launch(void* const* d_in, const int* in_sizes, int n_in,
                              void* d_out, int out_size, void* d_ws, size_t ws_size,
                              hipStream_t stream) {
    const float* x    = (const float*)d_in[0];
    const float* W    = (const float*)d_in[1];
    const float* bias = (const float*)d_in[2];
    float* out = (float*)d_out;

    __half2*  Wp   = (__half2*)((char*)d_ws + WP_OFF);
    unsigned* ctr  = (unsigned*)((char*)d_ws + CTR_OFF);
    unsigned* Sbuf = (unsigned*)((char*)d_ws + SBUF_OFF);

    hipMemsetAsync((char*)d_ws + CTR_OFF, 0, 4096, stream);
    wtrans_pack<<<dim3(16, 16), dim3(32, 8), 0, stream>>>(W, Wp);
    xs_gemm<<<dim3(1024, 8), 256, 0, stream>>>(x, W, bias, out);
    rnn_scan<<<NB_ * NH_, 512, 0, stream>>>(Wp, Sbuf, ctr, out);
}